// Round 7
// baseline (551.242 us; speedup 1.0000x reference)
//
#include <hip/hip_runtime.h>
#include <cmath>

// Problem constants
#define B_TOTAL 262144
#define D 16
#define TE 3
#define H 64

#define TPB 16                       // b-tiles (of 16 rows) per wave
#define NBX (B_TOTAL / 16 / TPB)     // 1024 blocks in x
#define NBY 4                        // d-groups of 4 (4 waves/block, one d each)

#define LOG2E 1.44269504088896340736f
#define LN2   0.693147180559945309417f

// f16 transpose buffer row stride (f16 elems). 72 = 64+8 pad: breaks pow2 bank
// aliasing; b128 reads stay 16B-aligned ((lm*72+8q)*2 % 16 == 0).
#define RSH 72

typedef _Float16 half8  __attribute__((ext_vector_type(8)));
typedef __fp16   fp16x2 __attribute__((ext_vector_type(2)));   // cvt_pkrtz return type
typedef float    f32x4  __attribute__((ext_vector_type(4)));
typedef unsigned int uint32;

// log2-domain softplus: log2(1 + 2^xs). Scale factors pre-folded into weights:
// W1,b1,b2 carry log2e; W3 carries ln2; ln2*log2e==1 so W2 is raw.
__device__ __forceinline__ float sp_log2(float xs) {
    return __builtin_amdgcn_logf(1.0f + __builtin_amdgcn_exp2f(xs));
}
// exact softplus for the final (unscaled) output
__device__ __forceinline__ float softplus_full(float x) {
    float e = __builtin_amdgcn_exp2f(-fabsf(x) * LOG2E);
    return fmaxf(x, 0.0f) + LN2 * __builtin_amdgcn_logf(1.0f + e);
}

// 256-thread blocks (4 waves): R3-R6 showed 1024-thread WGs pin occupancy at
// ~45% (1 WG/CU regardless of LDS 40-74KB / VGPR 60) -> small WGs so 8 blocks
// = 32 waves can co-reside. Wave w owns d = 4*blockIdx.y + w. Per 16-row tile:
// L1 MFMA (bias via constant-1 column) -> softplus -> f16 LDS transpose ->
// L2 MFMA -> softplus -> transpose -> L3 MFMA (replicated-column W3) -> obuf.
// One barrier per block (obuf columns wave-disjoint, tbuf wave-private).
__global__ __launch_bounds__(256, 8) void DiagonalVariance_kernel(
    const float* __restrict__ t,   // [B, TE]
    const float* __restrict__ y,   // [B, D]
    const float* __restrict__ W1,  // [D, 4, 64]
    const float* __restrict__ b1,  // [D, 64]
    const float* __restrict__ W2,  // [D, 64, 64]
    const float* __restrict__ b2,  // [D, 64]
    const float* __restrict__ W3,  // [D, 64, 1]
    const float* __restrict__ b3,  // [D, 1]
    float* __restrict__ out)       // [B, D]
{
    __shared__ __align__(16) _Float16 tbuf[4 * 16 * RSH];  // 9.2 KB (per-wave slices)
    __shared__ __align__(16) float obuf[TPB * 16 * 4];     // 4 KB: [row_local][dd]

    const int wave = threadIdx.x >> 6;
    const int lane = threadIdx.x & 63;
    const int q    = lane >> 4;
    const int lm   = lane & 15;
    const int d    = blockIdx.y * 4 + wave;
    const bool q0  = (q == 0);

    const float* __restrict__ W1d = W1 + d * (4 * H);
    const float* __restrict__ b1d = b1 + d * H;
    const float* __restrict__ W2d = W2 + d * (H * H);
    const float* __restrict__ b2d = b2 + d * H;
    const float* __restrict__ W3d = W3 + d * H;

    // ---------------- one-time per-wave fragment setup ----------------
    // W2 B-frags (raw): B[n=16nt+lm][k=32ks+8q+j]
    half8 w2f[2][4];
    #pragma unroll
    for (int ks = 0; ks < 2; ++ks)
        #pragma unroll
        for (int nt = 0; nt < 4; ++nt)
            #pragma unroll
            for (int j = 0; j < 8; ++j)
                w2f[ks][nt][j] = (_Float16)W2d[(32 * ks + 8 * q + j) * H + 16 * nt + lm];

    // W1 B-frags (scaled by log2e), bias b1*log2e in the k=4 row; zero rows
    // k>=5 make A-side garbage lanes harmless.
    half8 w1f[4];
    #pragma unroll
    for (int nt = 0; nt < 4; ++nt) {
        #pragma unroll
        for (int j = 0; j < 8; ++j) {
            const int h = 16 * nt + lm;
            float v = 0.0f;
            if (q0 && j < 4)  v = W1d[j * H + h] * LOG2E;
            if (q0 && j == 4) v = b1d[h] * LOG2E;
            w1f[nt][j] = (_Float16)v;
        }
    }

    // W3 B-frag (scaled by ln2), replicated across all n columns.
    half8 w3f[2];
    #pragma unroll
    for (int ks = 0; ks < 2; ++ks)
        #pragma unroll
        for (int j = 0; j < 8; ++j)
            w3f[ks][j] = (_Float16)(W3d[32 * ks + 8 * q + j] * LN2);

    // b2 (scaled) as C-init fragments: col=16nt+lm, replicated over rows.
    f32x4 b2f[4];
    #pragma unroll
    for (int nt = 0; nt < 4; ++nt) {
        const float bv = b2d[16 * nt + lm] * LOG2E;
        b2f[nt] = (f32x4){bv, bv, bv, bv};
    }
    const float b3v = b3[d];

    // f16 LDS transpose bases (per-wave slice, immediate offsets per access)
    _Float16* const tb  = tbuf + wave * (16 * RSH);
    _Float16* const twr = tb + (q * 4) * RSH + lm;       // + r*RSH + nt*16
    const _Float16* const trd = tb + lm * RSH + 8 * q;   // + 32*ks

    #pragma unroll 1
    for (int tg = 0; tg < TPB; ++tg) {
        const int tile = blockIdx.x * TPB + tg;
        const int row  = tile * 16 + lm;

        // ---- A-frag: k = [y, t0, t1, t2, 1(bias), 0,...] ----
        const float* tp = t + row * TE;
        const float x0 = y[row * D + d];
        const float t0 = tp[0];
        const float t1 = tp[1];
        const float t2 = tp[2];
        union { half8 h; fp16x2 p[4]; uint32 u[4]; } af;
        af.p[0] = __builtin_amdgcn_cvt_pkrtz(x0, t0);
        af.p[1] = __builtin_amdgcn_cvt_pkrtz(t1, t2);
        af.u[2] = 0x00003C00u;   // {1.0h, 0h} — bias multiplier at k=4
        af.u[3] = 0u;

        // ---- layer 1: acc1 = (x*W1 + b1)*log2e, C = 0 ----
        f32x4 acc1[4];
        #pragma unroll
        for (int nt = 0; nt < 4; ++nt)
            acc1[nt] = __builtin_amdgcn_mfma_f32_16x16x32_f16(
                af.h, w1f[nt], (f32x4){0.f, 0.f, 0.f, 0.f}, 0, 0, 0);

        // ---- softplus (log2 domain) -> f16 LDS transpose (C -> A layout) ----
        #pragma unroll
        for (int nt = 0; nt < 4; ++nt)
            #pragma unroll
            for (int r = 0; r < 4; ++r)
                twr[r * RSH + nt * 16] = (_Float16)sp_log2(acc1[nt][r]);

        // ---- layer-2 A-frags straight from LDS ----
        half8 a2[2];
        #pragma unroll
        for (int ks = 0; ks < 2; ++ks)
            a2[ks] = *(const half8*)(trd + 32 * ks);

        // ---- layer 2: C-init = b2*log2e ----
        f32x4 acc2[4];
        #pragma unroll
        for (int nt = 0; nt < 4; ++nt)
            acc2[nt] = __builtin_amdgcn_mfma_f32_16x16x32_f16(a2[0], w2f[0][nt], b2f[nt], 0, 0, 0);
        #pragma unroll
        for (int nt = 0; nt < 4; ++nt)
            acc2[nt] = __builtin_amdgcn_mfma_f32_16x16x32_f16(a2[1], w2f[1][nt], acc2[nt], 0, 0, 0);

        // ---- softplus -> same LDS transpose (same-wave DS ordering) ----
        #pragma unroll
        for (int nt = 0; nt < 4; ++nt)
            #pragma unroll
            for (int r = 0; r < 4; ++r)
                twr[r * RSH + nt * 16] = (_Float16)sp_log2(acc2[nt][r]);

        half8 a3[2];
        #pragma unroll
        for (int ks = 0; ks < 2; ++ks)
            a3[ks] = *(const half8*)(trd + 32 * ks);

        // ---- layer 3: every column of D3 = sum_k L[b,k]*W3[k]*ln2 ----
        f32x4 acc3;
        acc3 = __builtin_amdgcn_mfma_f32_16x16x32_f16(a3[0], w3f[0], (f32x4){0.f, 0.f, 0.f, 0.f}, 0, 0, 0);
        acc3 = __builtin_amdgcn_mfma_f32_16x16x32_f16(a3[1], w3f[1], acc3, 0, 0, 0);

        // lane lm<4 takes reg r=lm -> row q*4+lm; all 16 rows covered.
        const float v01 = (lm & 1) ? acc3[1] : acc3[0];
        const float v23 = (lm & 1) ? acc3[3] : acc3[2];
        const float vs  = (lm & 2) ? v23 : v01;
        if (lm < 4)
            obuf[(tg * 16 + q * 4 + lm) * 4 + wave] = softplus_full(vs + b3v);
    }

    // Single barrier, then f32x4 flush: thread i handles row i (256 rows),
    // writing out[(blockIdx.x*256 + i)*16 + blockIdx.y*4 .. +3].
    __syncthreads();
    const int i = threadIdx.x;
    const f32x4 v = *(const f32x4*)(obuf + 4 * i);
    *(f32x4*)(out + (blockIdx.x * 256 + i) * D + blockIdx.y * 4) = v;
}

extern "C" void kernel_launch(void* const* d_in, const int* in_sizes, int n_in,
                              void* d_out, int out_size, void* d_ws, size_t ws_size,
                              hipStream_t stream) {
    const float* t  = (const float*)d_in[0];
    const float* y  = (const float*)d_in[1];
    const float* W1 = (const float*)d_in[2];
    const float* b1 = (const float*)d_in[3];
    const float* W2 = (const float*)d_in[4];
    const float* b2 = (const float*)d_in[5];
    const float* W3 = (const float*)d_in[6];
    const float* b3 = (const float*)d_in[7];
    float* out = (float*)d_out;

    DiagonalVariance_kernel<<<dim3(NBX, NBY), dim3(256), 0, stream>>>(
        t, y, W1, b1, W2, b2, W3, b3, out);
}

// Round 9
// 212.840 us; speedup vs baseline: 2.5899x; 2.5899x over previous
//
#include <hip/hip_runtime.h>
#include <cmath>

// Problem constants
#define B_TOTAL 262144
#define D 16
#define TE 3
#define H 64

#define TPB 16                       // b-tiles (of 16 rows) per wave
#define NBX (B_TOTAL / 16 / TPB)     // 1024 blocks in x
#define NBY 4                        // d-groups of 4 (4 waves/block, one d each)

#define LOG2E 1.44269504088896340736f
#define LN2   0.693147180559945309417f

// f16 transpose buffer row stride (f16 elems). 72 = 64+8 pad: breaks pow2 bank
// aliasing; b128 reads stay 16B-aligned ((lm*72+8q)*2 % 16 == 0).
#define RSH 72

typedef _Float16 half8  __attribute__((ext_vector_type(8)));
typedef _Float16 half4  __attribute__((ext_vector_type(4)));
typedef __fp16   fp16x2 __attribute__((ext_vector_type(2)));   // cvt_pkrtz return type
typedef float    f32x4  __attribute__((ext_vector_type(4)));
typedef unsigned int uint32;

// log2-domain softplus: log2(1 + 2^xs). Scale factors pre-folded into weights:
// W1,b1,b2 carry log2e; W3 carries ln2; ln2*log2e==1 so W2 is raw.
__device__ __forceinline__ float sp_log2(float xs) {
    return __builtin_amdgcn_logf(1.0f + __builtin_amdgcn_exp2f(xs));
}
// exact softplus for the final (unscaled) output
__device__ __forceinline__ float softplus_full(float x) {
    float e = __builtin_amdgcn_exp2f(-fabsf(x) * LOG2E);
    return fmaxf(x, 0.0f) + LN2 * __builtin_amdgcn_logf(1.0f + e);
}

// 256-thread WGs (R7: occupancy scales, 86%) with a register diet so the
// fragments FIT (R7's cap=64 spilled catastrophically: FETCH 1.4GB).
// launch_bounds(256,5) -> ~102 VGPR cap vs ~93 needed. Wave w owns
// d = 4*blockIdx.y + w. Per 16-row tile: L1 via 16x16x16 MFMA (K=16 is
// enough for 5 k-slots; bias via constant-1 at k=4, garbage lanes killed by
// zero B rows) -> softplus -> f16 LDS transpose -> L2 16x16x32 MFMA (C=0,
// b2 added in epilogue: saves 12 regs vs replicated C-init) -> softplus ->
// transpose -> L3 MFMA (replicated-column W3) -> staged coalesced store.
__global__ __launch_bounds__(256, 5) void DiagonalVariance_kernel(
    const float* __restrict__ t,   // [B, TE]
    const float* __restrict__ y,   // [B, D]
    const float* __restrict__ W1,  // [D, 4, 64]
    const float* __restrict__ b1,  // [D, 64]
    const float* __restrict__ W2,  // [D, 64, 64]
    const float* __restrict__ b2,  // [D, 64]
    const float* __restrict__ W3,  // [D, 64, 1]
    const float* __restrict__ b3,  // [D, 1]
    float* __restrict__ out)       // [B, D]
{
    __shared__ __align__(16) _Float16 tbuf[4 * 16 * RSH];  // 9.2 KB (per-wave slices)
    __shared__ __align__(16) float obuf[TPB * 16 * 4];     // 4 KB: [row_local][dd]

    const int wave = threadIdx.x >> 6;
    const int lane = threadIdx.x & 63;
    const int q    = lane >> 4;
    const int lm   = lane & 15;
    const int d    = blockIdx.y * 4 + wave;
    const bool q0  = (q == 0);

    const float* __restrict__ W1d = W1 + d * (4 * H);
    const float* __restrict__ b1d = b1 + d * H;
    const float* __restrict__ W2d = W2 + d * (H * H);
    const float* __restrict__ b2d = b2 + d * H;
    const float* __restrict__ W3d = W3 + d * H;

    // ---------------- one-time per-wave fragment setup ----------------
    // W2 B-frags (raw): B[n=16nt+lm][k=32ks+8q+j]   (32 VGPRs)
    half8 w2f[2][4];
    #pragma unroll
    for (int ks = 0; ks < 2; ++ks)
        #pragma unroll
        for (int nt = 0; nt < 4; ++nt)
            #pragma unroll
            for (int j = 0; j < 8; ++j)
                w2f[ks][nt][j] = (_Float16)W2d[(32 * ks + 8 * q + j) * H + 16 * nt + lm];

    // W1 B-frags for 16x16x16 MFMA (8 VGPRs): B[n=16nt+lm][k=4q+i], scaled by
    // log2e; bias b1*log2e at k=4 (q1,i=0); rows k>=5 zero.
    half4 w1f[4];
    #pragma unroll
    for (int nt = 0; nt < 4; ++nt) {
        #pragma unroll
        for (int i = 0; i < 4; ++i) {
            const int h = 16 * nt + lm;
            float v = 0.0f;
            if (q == 0)           v = W1d[i * H + h] * LOG2E;
            if (q == 1 && i == 0) v = b1d[h] * LOG2E;
            w1f[nt][i] = (_Float16)v;
        }
    }

    // W3 B-frag (scaled by ln2), replicated across all n columns (8 VGPRs).
    half8 w3f[2];
    #pragma unroll
    for (int ks = 0; ks < 2; ++ks)
        #pragma unroll
        for (int j = 0; j < 8; ++j)
            w3f[ks][j] = (_Float16)(W3d[32 * ks + 8 * q + j] * LN2);

    // b2 (scaled) as one scalar per nt (4 VGPRs), added in the L2 epilogue.
    float b2s[4];
    #pragma unroll
    for (int nt = 0; nt < 4; ++nt)
        b2s[nt] = b2d[16 * nt + lm] * LOG2E;
    const float b3v = b3[d];

    // f16 LDS transpose bases (per-wave slice, immediate offsets per access)
    _Float16* const tb  = tbuf + wave * (16 * RSH);
    _Float16* const twr = tb + (q * 4) * RSH + lm;       // + r*RSH + nt*16
    const _Float16* const trd = tb + lm * RSH + 8 * q;   // + 32*ks

    #pragma unroll 1
    for (int tg = 0; tg < TPB; ++tg) {
        const int row = (blockIdx.x * TPB + tg) * 16 + lm;

        // ---- A-frag (16x16x16): lane(q,lm): m=lm, k=4q+i.
        // q0: {y,t0,t1,t2}; q1: {1,0,0,0} (bias row k=4); q2/q3: garbage
        // annihilated by zero B rows k>=5.
        const float* tp = t + row * TE;
        const float x0 = y[row * D + d];
        const float t0 = tp[0];
        const float t1 = tp[1];
        const float t2 = tp[2];
        union { half4 h; uint32 u[2]; } af;
        const fp16x2 p0 = __builtin_amdgcn_cvt_pkrtz(x0, t0);
        const fp16x2 p1 = __builtin_amdgcn_cvt_pkrtz(t1, t2);
        af.u[0] = q0 ? __builtin_bit_cast(uint32, p0) : 0x00003C00u;
        af.u[1] = q0 ? __builtin_bit_cast(uint32, p1) : 0u;

        // ---- layer 1: acc1 = (x*W1 + b1)*log2e, C = 0 ----
        f32x4 acc1[4];
        #pragma unroll
        for (int nt = 0; nt < 4; ++nt)
            acc1[nt] = __builtin_amdgcn_mfma_f32_16x16x16f16(
                af.h, w1f[nt], (f32x4){0.f, 0.f, 0.f, 0.f}, 0, 0, 0);

        // ---- softplus (log2 domain) -> f16 LDS transpose (C -> A layout) ----
        #pragma unroll
        for (int nt = 0; nt < 4; ++nt)
            #pragma unroll
            for (int r = 0; r < 4; ++r)
                twr[r * RSH + nt * 16] = (_Float16)sp_log2(acc1[nt][r]);

        // ---- layer-2 A-frags straight from LDS ----
        half8 a2[2];
        #pragma unroll
        for (int ks = 0; ks < 2; ++ks)
            a2[ks] = *(const half8*)(trd + 32 * ks);

        // ---- layer 2: C = 0, b2 added in epilogue ----
        f32x4 acc2[4];
        #pragma unroll
        for (int nt = 0; nt < 4; ++nt)
            acc2[nt] = __builtin_amdgcn_mfma_f32_16x16x32_f16(
                a2[0], w2f[0][nt], (f32x4){0.f, 0.f, 0.f, 0.f}, 0, 0, 0);
        #pragma unroll
        for (int nt = 0; nt < 4; ++nt)
            acc2[nt] = __builtin_amdgcn_mfma_f32_16x16x32_f16(a2[1], w2f[1][nt], acc2[nt], 0, 0, 0);

        // ---- softplus(acc2 + b2) -> same LDS transpose ----
        #pragma unroll
        for (int nt = 0; nt < 4; ++nt)
            #pragma unroll
            for (int r = 0; r < 4; ++r)
                twr[r * RSH + nt * 16] = (_Float16)sp_log2(acc2[nt][r] + b2s[nt]);

        half8 a3[2];
        #pragma unroll
        for (int ks = 0; ks < 2; ++ks)
            a3[ks] = *(const half8*)(trd + 32 * ks);

        // ---- layer 3: every column of D3 = sum_k L[b,k]*W3[k]*ln2 ----
        f32x4 acc3;
        acc3 = __builtin_amdgcn_mfma_f32_16x16x32_f16(a3[0], w3f[0], (f32x4){0.f, 0.f, 0.f, 0.f}, 0, 0, 0);
        acc3 = __builtin_amdgcn_mfma_f32_16x16x32_f16(a3[1], w3f[1], acc3, 0, 0, 0);

        // lane lm<4 takes reg r=lm -> row q*4+lm; all 16 rows covered.
        const float v01 = (lm & 1) ? acc3[1] : acc3[0];
        const float v23 = (lm & 1) ? acc3[3] : acc3[2];
        const float vs  = (lm & 2) ? v23 : v01;
        if (lm < 4)
            obuf[(tg * 16 + q * 4 + lm) * 4 + wave] = softplus_full(vs + b3v);
    }

    // Single barrier, then f32x4 flush: thread i handles row i (256 rows),
    // writing out[(blockIdx.x*256 + i)*16 + blockIdx.y*4 .. +3].
    __syncthreads();
    const int i = threadIdx.x;
    const f32x4 v = *(const f32x4*)(obuf + 4 * i);
    *(f32x4*)(out + (blockIdx.x * 256 + i) * D + blockIdx.y * 4) = v;
}

extern "C" void kernel_launch(void* const* d_in, const int* in_sizes, int n_in,
                              void* d_out, int out_size, void* d_ws, size_t ws_size,
                              hipStream_t stream) {
    const float* t  = (const float*)d_in[0];
    const float* y  = (const float*)d_in[1];
    const float* W1 = (const float*)d_in[2];
    const float* b1 = (const float*)d_in[3];
    const float* W2 = (const float*)d_in[4];
    const float* b2 = (const float*)d_in[5];
    const float* W3 = (const float*)d_in[6];
    const float* b3 = (const float*)d_in[7];
    float* out = (float*)d_out;

    DiagonalVariance_kernel<<<dim3(NBX, NBY), dim3(256), 0, stream>>>(
        t, y, W1, b1, W2, b2, W3, b3, out);
}

// Round 10
// 209.352 us; speedup vs baseline: 2.6331x; 1.0167x over previous
//
#include <hip/hip_runtime.h>
#include <cmath>

// Problem constants
#define B_TOTAL 262144
#define D 16
#define TE 3
#define H 64

#define TPB 16                       // b-tiles (of 16 rows) per wave
#define NBX (B_TOTAL / 16 / TPB)     // 1024 blocks in x
#define NBY 4                        // d-groups of 4 (4 waves/block, one d each)

#define LOG2E 1.44269504088896340736f
#define LN2   0.693147180559945309417f

// f16 transpose buffer row stride (f16 elems). 72 = 64+8 pad: breaks pow2 bank
// aliasing; b128 reads stay 16B-aligned.
#define RSH 72
// A-frag staging stride in dwords. 10 (40B): banks 10*lm mod 32 all distinct
// for lm=0..15 -> conflict-free ds_read_b64; 8B alignment holds.
#define ARS 10

typedef _Float16 half8  __attribute__((ext_vector_type(8)));
typedef _Float16 half4  __attribute__((ext_vector_type(4)));
typedef __fp16   fp16x2 __attribute__((ext_vector_type(2)));   // cvt_pkrtz return type
typedef float    f32x4  __attribute__((ext_vector_type(4)));
typedef unsigned int uint32;

// log2-domain softplus: log2(1 + 2^xs). Scale factors pre-folded into weights:
// W1,b1,b2 carry log2e; W3 carries ln2; ln2*log2e==1 so W2 is raw.
__device__ __forceinline__ float sp_log2(float xs) {
    return __builtin_amdgcn_logf(1.0f + __builtin_amdgcn_exp2f(xs));
}
// exact softplus for the final (unscaled) output
__device__ __forceinline__ float softplus_full(float x) {
    float e = __builtin_amdgcn_exp2f(-fabsf(x) * LOG2E);
    return fmaxf(x, 0.0f) + LN2 * __builtin_amdgcn_logf(1.0f + e);
}

// R9 structure (256-thd WG, K=16 L1, b2 epilogue add) + cooperative input
// staging: R9's per-tile y/t gathers (64B-stride, 4x quad-duplicated, 4 VMEM
// per tile) are hoisted to one block-start pass that pre-packs the L1 A-frag
// halves into LDS. Per tile the A-frag is then 1 conflict-free ds_read_b64.
__global__ __launch_bounds__(256, 5) void DiagonalVariance_kernel(
    const float* __restrict__ t,   // [B, TE]
    const float* __restrict__ y,   // [B, D]
    const float* __restrict__ W1,  // [D, 4, 64]
    const float* __restrict__ b1,  // [D, 64]
    const float* __restrict__ W2,  // [D, 64, 64]
    const float* __restrict__ b2,  // [D, 64]
    const float* __restrict__ W3,  // [D, 64, 1]
    const float* __restrict__ b3,  // [D, 1]
    float* __restrict__ out)       // [B, D]
{
    __shared__ __align__(16) _Float16 tbuf[4 * 16 * RSH];  // 9.2 KB (per-wave slices)
    __shared__ __align__(16) float obuf[TPB * 16 * 4];     // 4 KB: [row_local][dd]
    __shared__ __align__(16) uint32 abuf[256 * ARS];       // 10 KB: [row][{u0_d,u1}x4]

    const int wave = threadIdx.x >> 6;
    const int lane = threadIdx.x & 63;
    const int q    = lane >> 4;
    const int lm   = lane & 15;
    const int d    = blockIdx.y * 4 + wave;
    const bool q0  = (q == 0);

    // ---- cooperative input staging: thread i pre-packs row i's A-frag ----
    {
        const int i    = threadIdx.x;
        const int grow = blockIdx.x * 256 + i;
        const f32x4 yv = *(const f32x4*)(y + grow * D + blockIdx.y * 4);
        const float* tpp = t + grow * TE;
        const float tt0 = tpp[0], tt1 = tpp[1], tt2 = tpp[2];
        const uint32 u1 = __builtin_bit_cast(uint32, __builtin_amdgcn_cvt_pkrtz(tt1, tt2));
        uint32* ab = abuf + i * ARS;
        ab[0] = __builtin_bit_cast(uint32, __builtin_amdgcn_cvt_pkrtz(yv.x, tt0)); ab[1] = u1;
        ab[2] = __builtin_bit_cast(uint32, __builtin_amdgcn_cvt_pkrtz(yv.y, tt0)); ab[3] = u1;
        ab[4] = __builtin_bit_cast(uint32, __builtin_amdgcn_cvt_pkrtz(yv.z, tt0)); ab[5] = u1;
        ab[6] = __builtin_bit_cast(uint32, __builtin_amdgcn_cvt_pkrtz(yv.w, tt0)); ab[7] = u1;
    }

    const float* __restrict__ W1d = W1 + d * (4 * H);
    const float* __restrict__ b1d = b1 + d * H;
    const float* __restrict__ W2d = W2 + d * (H * H);
    const float* __restrict__ b2d = b2 + d * H;
    const float* __restrict__ W3d = W3 + d * H;

    // ---------------- one-time per-wave fragment setup ----------------
    // W2 B-frags (raw): B[n=16nt+lm][k=32ks+8q+j]
    half8 w2f[2][4];
    #pragma unroll
    for (int ks = 0; ks < 2; ++ks)
        #pragma unroll
        for (int nt = 0; nt < 4; ++nt)
            #pragma unroll
            for (int j = 0; j < 8; ++j)
                w2f[ks][nt][j] = (_Float16)W2d[(32 * ks + 8 * q + j) * H + 16 * nt + lm];

    // W1 B-frags for 16x16x16 MFMA: B[n=16nt+lm][k=4q+i], scaled by log2e;
    // bias b1*log2e at k=4 (q1,i=0); rows k>=5 zero (kill A garbage lanes).
    half4 w1f[4];
    #pragma unroll
    for (int nt = 0; nt < 4; ++nt) {
        #pragma unroll
        for (int i = 0; i < 4; ++i) {
            const int h = 16 * nt + lm;
            float v = 0.0f;
            if (q == 0)           v = W1d[i * H + h] * LOG2E;
            if (q == 1 && i == 0) v = b1d[h] * LOG2E;
            w1f[nt][i] = (_Float16)v;
        }
    }

    // W3 B-frag (scaled by ln2), replicated across all n columns.
    half8 w3f[2];
    #pragma unroll
    for (int ks = 0; ks < 2; ++ks)
        #pragma unroll
        for (int j = 0; j < 8; ++j)
            w3f[ks][j] = (_Float16)(W3d[32 * ks + 8 * q + j] * LN2);

    // b2 (scaled) as one scalar per nt, added in the L2 epilogue.
    float b2s[4];
    #pragma unroll
    for (int nt = 0; nt < 4; ++nt)
        b2s[nt] = b2d[16 * nt + lm] * LOG2E;
    const float b3v = b3[d];

    // f16 LDS transpose bases (per-wave slice, immediate offsets per access)
    _Float16* const tb  = tbuf + wave * (16 * RSH);
    _Float16* const twr = tb + (q * 4) * RSH + lm;       // + r*RSH + nt*16
    const _Float16* const trd = tb + lm * RSH + 8 * q;   // + 32*ks

    // staged A-frag base for this wave: + tg*16*ARS per tile (imm offset)
    const uint32* const ard = abuf + lm * ARS + 2 * wave;

    __syncthreads();   // staging visible to all waves

    #pragma unroll 1
    for (int tg = 0; tg < TPB; ++tg) {
        // ---- A-frag from staged LDS: 1 ds_read_b64 + 2 cndmask ----
        const uint32 a0 = ard[tg * 16 * ARS + 0];
        const uint32 a1 = ard[tg * 16 * ARS + 1];
        union { half4 h; uint32 u[2]; } af;
        af.u[0] = q0 ? a0 : 0x00003C00u;   // q1: {1.0h,0} bias row k=4
        af.u[1] = q0 ? a1 : 0u;            // q2/q3 garbage killed by zero B rows

        // ---- layer 1: acc1 = (x*W1 + b1)*log2e, C = 0 ----
        f32x4 acc1[4];
        #pragma unroll
        for (int nt = 0; nt < 4; ++nt)
            acc1[nt] = __builtin_amdgcn_mfma_f32_16x16x16f16(
                af.h, w1f[nt], (f32x4){0.f, 0.f, 0.f, 0.f}, 0, 0, 0);

        // ---- softplus (log2 domain) -> f16 LDS transpose (C -> A layout) ----
        #pragma unroll
        for (int nt = 0; nt < 4; ++nt)
            #pragma unroll
            for (int r = 0; r < 4; ++r)
                twr[r * RSH + nt * 16] = (_Float16)sp_log2(acc1[nt][r]);

        // ---- layer-2 A-frags straight from LDS ----
        half8 a2[2];
        #pragma unroll
        for (int ks = 0; ks < 2; ++ks)
            a2[ks] = *(const half8*)(trd + 32 * ks);

        // ---- layer 2: C = 0, b2 added in epilogue ----
        f32x4 acc2[4];
        #pragma unroll
        for (int nt = 0; nt < 4; ++nt)
            acc2[nt] = __builtin_amdgcn_mfma_f32_16x16x32_f16(
                a2[0], w2f[0][nt], (f32x4){0.f, 0.f, 0.f, 0.f}, 0, 0, 0);
        #pragma unroll
        for (int nt = 0; nt < 4; ++nt)
            acc2[nt] = __builtin_amdgcn_mfma_f32_16x16x32_f16(a2[1], w2f[1][nt], acc2[nt], 0, 0, 0);

        // ---- softplus(acc2 + b2) -> same LDS transpose ----
        #pragma unroll
        for (int nt = 0; nt < 4; ++nt)
            #pragma unroll
            for (int r = 0; r < 4; ++r)
                twr[r * RSH + nt * 16] = (_Float16)sp_log2(acc2[nt][r] + b2s[nt]);

        half8 a3[2];
        #pragma unroll
        for (int ks = 0; ks < 2; ++ks)
            a3[ks] = *(const half8*)(trd + 32 * ks);

        // ---- layer 3: every column of D3 = sum_k L[b,k]*W3[k]*ln2 ----
        f32x4 acc3;
        acc3 = __builtin_amdgcn_mfma_f32_16x16x32_f16(a3[0], w3f[0], (f32x4){0.f, 0.f, 0.f, 0.f}, 0, 0, 0);
        acc3 = __builtin_amdgcn_mfma_f32_16x16x32_f16(a3[1], w3f[1], acc3, 0, 0, 0);

        // lane lm<4 takes reg r=lm -> row q*4+lm; all 16 rows covered.
        const float v01 = (lm & 1) ? acc3[1] : acc3[0];
        const float v23 = (lm & 1) ? acc3[3] : acc3[2];
        const float vs  = (lm & 2) ? v23 : v01;
        if (lm < 4)
            obuf[(tg * 16 + q * 4 + lm) * 4 + wave] = softplus_full(vs + b3v);
    }

    // Single barrier, then f32x4 flush: thread i handles row i (256 rows),
    // writing out[(blockIdx.x*256 + i)*16 + blockIdx.y*4 .. +3].
    __syncthreads();
    const int i = threadIdx.x;
    const f32x4 v = *(const f32x4*)(obuf + 4 * i);
    *(f32x4*)(out + (blockIdx.x * 256 + i) * D + blockIdx.y * 4) = v;
}

extern "C" void kernel_launch(void* const* d_in, const int* in_sizes, int n_in,
                              void* d_out, int out_size, void* d_ws, size_t ws_size,
                              hipStream_t stream) {
    const float* t  = (const float*)d_in[0];
    const float* y  = (const float*)d_in[1];
    const float* W1 = (const float*)d_in[2];
    const float* b1 = (const float*)d_in[3];
    const float* W2 = (const float*)d_in[4];
    const float* b2 = (const float*)d_in[5];
    const float* W3 = (const float*)d_in[6];
    const float* b3 = (const float*)d_in[7];
    float* out = (float*)d_out;

    DiagonalVariance_kernel<<<dim3(NBX, NBY), dim3(256), 0, stream>>>(
        t, y, W1, b1, W2, b2, W3, b3, out);
}